// Round 1
// baseline (444.735 us; speedup 1.0000x reference)
//
#include <hip/hip_runtime.h>

// Problem constants (fixed by the reference).
#define NXv    400
#define NYv    400
#define Bv     4
#define Cv     128
#define Sv     (NXv * NYv)      // 160000 spatial cells per batch
#define NCELLS (Bv * Sv)        // 640000 total cells
#define TILE   64               // cells per block; 160000 % 64 == 0 -> tile never crosses batch

// Build per-cell linked lists of voxel indices.
// head[cell] = last voxel seen; next[v] = previous head. Order-free (max is commutative).
__global__ __launch_bounds__(256) void build_lists_kernel(
        const int* __restrict__ batch_idx,
        const int* __restrict__ y_idx,
        const int* __restrict__ x_idx,
        int* __restrict__ head,
        int* __restrict__ nxt,
        int n_voxels) {
    int v = blockIdx.x * 256 + threadIdx.x;
    if (v >= n_voxels) return;
    int cell = batch_idx[v] * Sv + y_idx[v] * NXv + x_idx[v];
    int old = atomicExch(&head[cell], v);
    nxt[v] = old;
}

// One block = 64 consecutive cells (same batch b). 4 waves; wave w covers
// channels [w*32, w*32+32) in 8 float4 iterations. Lane l owns cell tile0+l.
// Every output element written exactly once (0 for empty cells).
__global__ __launch_bounds__(256) void gather_max_kernel(
        const float4* __restrict__ feat4,   // (N_VOXELS, 32) float4 view of (N,128) f32
        const int* __restrict__ head,
        const int* __restrict__ nxt,
        float* __restrict__ out) {          // (B, C, NY, NX)
    const int lane = threadIdx.x & 63;
    const int wave = threadIdx.x >> 6;
    const int cell0 = blockIdx.x * TILE;
    const int cell = cell0 + lane;
    const int b = cell0 / Sv;               // whole tile in one batch
    const int s = cell - b * Sv;            // y*NX + x
    const int h = head[cell];
    const int obase = b * (Cv * Sv) + s;    // max ~81.9M < 2^31, int is fine

    #pragma unroll
    for (int j = 0; j < 8; ++j) {
        const int c4 = wave * 8 + j;        // float4 column index; c = 4*c4
        float4 m = make_float4(-3.402823466e38f, -3.402823466e38f,
                               -3.402823466e38f, -3.402823466e38f);
        for (int v = h; v != -1; v = nxt[v]) {
            float4 f = feat4[v * (Cv / 4) + c4];
            m.x = fmaxf(m.x, f.x);
            m.y = fmaxf(m.y, f.y);
            m.z = fmaxf(m.z, f.z);
            m.w = fmaxf(m.w, f.w);
        }
        if (h == -1) {                      // empty cell -> zeros (reference: neginf -> 0)
            m = make_float4(0.f, 0.f, 0.f, 0.f);
        }
        const int c = c4 * 4;
        out[obase + (c + 0) * Sv] = m.x;
        out[obase + (c + 1) * Sv] = m.y;
        out[obase + (c + 2) * Sv] = m.z;
        out[obase + (c + 3) * Sv] = m.w;
    }
}

extern "C" void kernel_launch(void* const* d_in, const int* in_sizes, int n_in,
                              void* d_out, int out_size, void* d_ws, size_t ws_size,
                              hipStream_t stream) {
    const float* feat      = (const float*)d_in[0];   // (150000, 128) f32
    const int*   batch_idx = (const int*)d_in[1];
    const int*   y_idx     = (const int*)d_in[2];
    const int*   x_idx     = (const int*)d_in[3];
    // d_in[4] = batch_size scalar (compile-time Bv=4, unused)
    float* out = (float*)d_out;

    const int n_voxels = in_sizes[1];                 // 150000

    // Workspace layout: head[NCELLS] ints, next[n_voxels] ints (~3.2 MB).
    int* head = (int*)d_ws;
    int* nxt  = head + NCELLS;

    // head = -1 everywhere; next needs no init (written before any read).
    hipMemsetAsync(head, 0xFF, (size_t)NCELLS * sizeof(int), stream);

    build_lists_kernel<<<(n_voxels + 255) / 256, 256, 0, stream>>>(
        batch_idx, y_idx, x_idx, head, nxt, n_voxels);

    gather_max_kernel<<<NCELLS / TILE, 256, 0, stream>>>(
        (const float4*)feat, head, nxt, out);
}

// Round 3
// 420.010 us; speedup vs baseline: 1.0589x; 1.0589x over previous
//
#include <hip/hip_runtime.h>

// Problem constants (fixed by the reference).
#define NXv    400
#define NYv    400
#define Bv     4
#define Cv     128
#define Sv     (NXv * NYv)      // 160000 spatial cells per batch
#define NCELLS (Bv * Sv)        // 640000 total cells
#define TILE   64               // cells per block; 160000 % 64 == 0 -> tile never crosses batch

#define NEG_FLT_MAX (-3.402823466e38f)

// Build per-cell linked lists of voxel indices.
// head[cell] = last voxel seen; next[v] = previous head. Order-free (max is commutative).
__global__ __launch_bounds__(256) void build_lists_kernel(
        const int* __restrict__ batch_idx,
        const int* __restrict__ y_idx,
        const int* __restrict__ x_idx,
        int* __restrict__ head,
        int* __restrict__ nxt,
        int n_voxels) {
    int v = blockIdx.x * 256 + threadIdx.x;
    if (v >= n_voxels) return;
    int cell = batch_idx[v] * Sv + y_idx[v] * NXv + x_idx[v];
    int old = atomicExch(&head[cell], v);
    nxt[v] = old;
}

// One block = 64 consecutive cells (same batch b). 4 waves; wave w covers
// channels [w*32, w*32+32). Lane l owns cell tile0+l and walks its list ONCE,
// accumulating all 8 float4 (128 B contiguous) per visited voxel.
// Every output element written exactly once (0 for empty cells).
__global__ __launch_bounds__(256) void gather_max_kernel(
        const float4* __restrict__ feat4,   // (N_VOXELS, 32) float4 view of (N,128) f32
        const int* __restrict__ head,
        const int* __restrict__ nxt,
        float* __restrict__ out) {          // (B, C, NY, NX)
    const int lane = threadIdx.x & 63;
    const int wave = threadIdx.x >> 6;
    const int cell0 = blockIdx.x * TILE;
    const int cell = cell0 + lane;
    const int b = cell0 / Sv;               // whole tile in one batch
    const int s = cell - b * Sv;            // y*NX + x
    const int obase = b * (Cv * Sv) + s;    // max ~81.9M < 2^31, int is fine
    const int c4base = wave * 8;            // this wave's float4-column band

    int v = head[cell];
    const bool empty = (v < 0);

    float4 m[8];
    #pragma unroll
    for (int j = 0; j < 8; ++j)
        m[j] = make_float4(NEG_FLT_MAX, NEG_FLT_MAX, NEG_FLT_MAX, NEG_FLT_MAX);

    while (v >= 0) {
        const float4* __restrict__ row = feat4 + (size_t)v * (Cv / 4) + c4base;
        const int vn = nxt[v];              // issue chase early; overlaps feature loads
        #pragma unroll
        for (int j = 0; j < 8; ++j) {
            const float4 f = row[j];        // lane-contiguous 128 B across the unroll
            m[j].x = fmaxf(m[j].x, f.x);
            m[j].y = fmaxf(m[j].y, f.y);
            m[j].z = fmaxf(m[j].z, f.z);
            m[j].w = fmaxf(m[j].w, f.w);
        }
        v = vn;
    }

    if (empty) {                            // reference: neginf -> 0 for untouched cells
        #pragma unroll
        for (int j = 0; j < 8; ++j)
            m[j] = make_float4(0.f, 0.f, 0.f, 0.f);
    }

    #pragma unroll
    for (int j = 0; j < 8; ++j) {
        const int c = (c4base + j) * 4;
        out[obase + (c + 0) * Sv] = m[j].x;
        out[obase + (c + 1) * Sv] = m[j].y;
        out[obase + (c + 2) * Sv] = m[j].z;
        out[obase + (c + 3) * Sv] = m[j].w;
    }
}

extern "C" void kernel_launch(void* const* d_in, const int* in_sizes, int n_in,
                              void* d_out, int out_size, void* d_ws, size_t ws_size,
                              hipStream_t stream) {
    const float* feat      = (const float*)d_in[0];   // (150000, 128) f32
    const int*   batch_idx = (const int*)d_in[1];
    const int*   y_idx     = (const int*)d_in[2];
    const int*   x_idx     = (const int*)d_in[3];
    // d_in[4] = batch_size scalar (compile-time Bv=4, unused)
    float* out = (float*)d_out;

    const int n_voxels = in_sizes[1];                 // 150000

    // Workspace layout: head[NCELLS] ints, next[n_voxels] ints (~3.2 MB).
    int* head = (int*)d_ws;
    int* nxt  = head + NCELLS;

    // head = -1 everywhere; next needs no init (written before any read).
    hipMemsetAsync(head, 0xFF, (size_t)NCELLS * sizeof(int), stream);

    build_lists_kernel<<<(n_voxels + 255) / 256, 256, 0, stream>>>(
        batch_idx, y_idx, x_idx, head, nxt, n_voxels);

    gather_max_kernel<<<NCELLS / TILE, 256, 0, stream>>>(
        (const float4*)feat, head, nxt, out);
}

// Round 4
// 413.744 us; speedup vs baseline: 1.0749x; 1.0151x over previous
//
#include <hip/hip_runtime.h>

// Problem constants (fixed by the reference).
#define NXv    400
#define NYv    400
#define Bv     4
#define Cv     128
#define Sv     (NXv * NYv)      // 160000 spatial cells per batch
#define NCELLS (Bv * Sv)        // 640000 total cells
#define TILE   128              // cells per block; 160000 % 128 == 0 -> tile never crosses batch

#define NEG_FLT_MAX (-3.402823466e38f)

// Build per-cell linked lists of voxel indices.
// head[cell] = last voxel seen; next[v] = previous head. Order-free (max is commutative).
__global__ __launch_bounds__(256) void build_lists_kernel(
        const int* __restrict__ batch_idx,
        const int* __restrict__ y_idx,
        const int* __restrict__ x_idx,
        int* __restrict__ head,
        int* __restrict__ nxt,
        int n_voxels) {
    int v = blockIdx.x * 256 + threadIdx.x;
    if (v >= n_voxels) return;
    int cell = batch_idx[v] * Sv + y_idx[v] * NXv + x_idx[v];
    int old = atomicExch(&head[cell], v);
    nxt[v] = old;
}

__device__ __forceinline__ float4 fmax4(float4 a, float4 b) {
    return make_float4(fmaxf(a.x, b.x), fmaxf(a.y, b.y),
                       fmaxf(a.z, b.z), fmaxf(a.w, b.w));
}

// Block = 128 consecutive cells (one batch), 256 threads = 4 waves.
// Thread t: cell-quad sub = t&31 (cells tile0+sub*4 .. +3), channel band = t>>5
// (channels band*16 .. +15, i.e. float4 columns c4b..c4b+3).
// Walks its 4 lists INTERLEAVED (4-way chase MLP); per hop loads 64 B contiguous.
// Stores via in-register 4x4 transpose as dwordx4 along the spatial axis:
// per wave-store, lanes 0-31 cover 512 B contiguous (one channel plane).
__global__ __launch_bounds__(256) void gather_max_kernel(
        const float4* __restrict__ feat4,   // (N_VOXELS, 32) float4 view of (N,128) f32
        const int4*   __restrict__ head4,   // (NCELLS/4)
        const int*    __restrict__ nxt,
        float4*       __restrict__ out4) {  // (B, C, NY, NX) as float4 along x
    const int sub   = threadIdx.x & 31;
    const int band  = threadIdx.x >> 5;     // 0..7
    const int tile0 = blockIdx.x * TILE;
    const int b     = tile0 / Sv;           // whole tile in one batch
    const int s0    = tile0 - b * Sv + sub * 4;   // first spatial cell of quad
    const int c4b   = band * 4;             // float4-column base (channel = 4*(c4b+k)+comp)

    const int4 h = head4[blockIdx.x * (TILE / 4) + sub];
    int v0 = h.x, v1 = h.y, v2 = h.z, v3 = h.w;

    float4 a0[4], a1[4], a2[4], a3[4];
    #pragma unroll
    for (int k = 0; k < 4; ++k) {
        a0[k] = a1[k] = a2[k] = a3[k] =
            make_float4(NEG_FLT_MAX, NEG_FLT_MAX, NEG_FLT_MAX, NEG_FLT_MAX);
    }

    while ((v0 >= 0) | (v1 >= 0) | (v2 >= 0) | (v3 >= 0)) {
        if (v0 >= 0) {
            const float4* __restrict__ r = feat4 + (size_t)v0 * (Cv / 4) + c4b;
            const int vn = nxt[v0];
            a0[0] = fmax4(a0[0], r[0]); a0[1] = fmax4(a0[1], r[1]);
            a0[2] = fmax4(a0[2], r[2]); a0[3] = fmax4(a0[3], r[3]);
            v0 = vn;
        }
        if (v1 >= 0) {
            const float4* __restrict__ r = feat4 + (size_t)v1 * (Cv / 4) + c4b;
            const int vn = nxt[v1];
            a1[0] = fmax4(a1[0], r[0]); a1[1] = fmax4(a1[1], r[1]);
            a1[2] = fmax4(a1[2], r[2]); a1[3] = fmax4(a1[3], r[3]);
            v1 = vn;
        }
        if (v2 >= 0) {
            const float4* __restrict__ r = feat4 + (size_t)v2 * (Cv / 4) + c4b;
            const int vn = nxt[v2];
            a2[0] = fmax4(a2[0], r[0]); a2[1] = fmax4(a2[1], r[1]);
            a2[2] = fmax4(a2[2], r[2]); a2[3] = fmax4(a2[3], r[3]);
            v2 = vn;
        }
        if (v3 >= 0) {
            const float4* __restrict__ r = feat4 + (size_t)v3 * (Cv / 4) + c4b;
            const int vn = nxt[v3];
            a3[0] = fmax4(a3[0], r[0]); a3[1] = fmax4(a3[1], r[1]);
            a3[2] = fmax4(a3[2], r[2]); a3[3] = fmax4(a3[3], r[3]);
            v3 = vn;
        }
    }

    // Empty cells (head < 0): reference maps neginf -> 0.
    const float4 z4 = make_float4(0.f, 0.f, 0.f, 0.f);
    if (h.x < 0) { a0[0] = a0[1] = a0[2] = a0[3] = z4; }
    if (h.y < 0) { a1[0] = a1[1] = a1[2] = a1[3] = z4; }
    if (h.z < 0) { a2[0] = a2[1] = a2[2] = a2[3] = z4; }
    if (h.w < 0) { a3[0] = a3[1] = a3[2] = a3[3] = z4; }

    // Store: 4x4 in-register transpose -> float4 along spatial x.
    // out4 index = b*(Cv*Sv/4) + c*(Sv/4) + s0/4.
    const int obase = b * (Cv * (Sv / 4)) + (s0 >> 2);
    #pragma unroll
    for (int k = 0; k < 4; ++k) {
        const int c0 = (c4b + k) * 4;
        out4[obase + (c0 + 0) * (Sv / 4)] = make_float4(a0[k].x, a1[k].x, a2[k].x, a3[k].x);
        out4[obase + (c0 + 1) * (Sv / 4)] = make_float4(a0[k].y, a1[k].y, a2[k].y, a3[k].y);
        out4[obase + (c0 + 2) * (Sv / 4)] = make_float4(a0[k].z, a1[k].z, a2[k].z, a3[k].z);
        out4[obase + (c0 + 3) * (Sv / 4)] = make_float4(a0[k].w, a1[k].w, a2[k].w, a3[k].w);
    }
}

extern "C" void kernel_launch(void* const* d_in, const int* in_sizes, int n_in,
                              void* d_out, int out_size, void* d_ws, size_t ws_size,
                              hipStream_t stream) {
    const float* feat      = (const float*)d_in[0];   // (150000, 128) f32
    const int*   batch_idx = (const int*)d_in[1];
    const int*   y_idx     = (const int*)d_in[2];
    const int*   x_idx     = (const int*)d_in[3];
    // d_in[4] = batch_size scalar (compile-time Bv=4, unused)
    float* out = (float*)d_out;

    const int n_voxels = in_sizes[1];                 // 150000

    // Workspace layout: head[NCELLS] ints, next[n_voxels] ints (~3.2 MB).
    int* head = (int*)d_ws;
    int* nxt  = head + NCELLS;

    // head = -1 everywhere; next needs no init (written before any read).
    hipMemsetAsync(head, 0xFF, (size_t)NCELLS * sizeof(int), stream);

    build_lists_kernel<<<(n_voxels + 255) / 256, 256, 0, stream>>>(
        batch_idx, y_idx, x_idx, head, nxt, n_voxels);

    gather_max_kernel<<<NCELLS / TILE, 256, 0, stream>>>(
        (const float4*)feat, (const int4*)head, nxt, (float4*)out);
}

// Round 5
// 411.212 us; speedup vs baseline: 1.0815x; 1.0062x over previous
//
#include <hip/hip_runtime.h>

// Problem constants (fixed by the reference).
#define NXv    400
#define NYv    400
#define Bv     4
#define Cv     128
#define Sv     (NXv * NYv)      // 160000 spatial cells per batch
#define NCELLS (Bv * Sv)        // 640000 total cells
#define TILE   128              // cells per block; 160000 % 128 == 0 -> tile never crosses batch

#define NEG_FLT_MAX (-3.402823466e38f)

typedef float v4f __attribute__((ext_vector_type(4)));

// Build per-cell linked lists of voxel indices.
// head[cell] = last voxel seen; next[v] = previous head. Order-free (max is commutative).
__global__ __launch_bounds__(256) void build_lists_kernel(
        const int* __restrict__ batch_idx,
        const int* __restrict__ y_idx,
        const int* __restrict__ x_idx,
        int* __restrict__ head,
        int* __restrict__ nxt,
        int n_voxels) {
    int v = blockIdx.x * 256 + threadIdx.x;
    if (v >= n_voxels) return;
    int cell = batch_idx[v] * Sv + y_idx[v] * NXv + x_idx[v];
    int old = atomicExch(&head[cell], v);
    nxt[v] = old;
}

__device__ __forceinline__ float4 fmax4(float4 a, float4 b) {
    return make_float4(fmaxf(a.x, b.x), fmaxf(a.y, b.y),
                       fmaxf(a.z, b.z), fmaxf(a.w, b.w));
}

// Streaming (non-temporal) float4 store: output is write-once, never re-read.
// Keeps the 328 MB output stream from evicting nxt/head/feature lines in L2.
__device__ __forceinline__ void nt_store4(float4* p, float4 v) {
    v4f t = { v.x, v.y, v.z, v.w };
    __builtin_nontemporal_store(t, (v4f*)p);
}

// Block = 128 consecutive cells (one batch), 256 threads = 4 waves.
// Thread t: cell-quad sub = t&31 (cells tile0+sub*4 .. +3), channel band = t>>5
// (channels band*16 .. +15, i.e. float4 columns c4b..c4b+3).
// Walks its 4 lists INTERLEAVED (4-way chase MLP); per hop loads 64 B contiguous
// (the band-pair within each wave completes 128 B lines).
// Stores via in-register 4x4 transpose as NT dwordx4 along the spatial axis.
__global__ __launch_bounds__(256) void gather_max_kernel(
        const float4* __restrict__ feat4,   // (N_VOXELS, 32) float4 view of (N,128) f32
        const int4*   __restrict__ head4,   // (NCELLS/4)
        const int*    __restrict__ nxt,
        float4*       __restrict__ out4) {  // (B, C, NY, NX) as float4 along x
    const int sub   = threadIdx.x & 31;
    const int band  = threadIdx.x >> 5;     // 0..7
    const int tile0 = blockIdx.x * TILE;
    const int b     = tile0 / Sv;           // whole tile in one batch
    const int s0    = tile0 - b * Sv + sub * 4;   // first spatial cell of quad
    const int c4b   = band * 4;             // float4-column base (channel = 4*(c4b+k)+comp)

    const int4 h = head4[blockIdx.x * (TILE / 4) + sub];
    int v0 = h.x, v1 = h.y, v2 = h.z, v3 = h.w;

    float4 a0[4], a1[4], a2[4], a3[4];
    #pragma unroll
    for (int k = 0; k < 4; ++k) {
        a0[k] = a1[k] = a2[k] = a3[k] =
            make_float4(NEG_FLT_MAX, NEG_FLT_MAX, NEG_FLT_MAX, NEG_FLT_MAX);
    }

    while ((v0 >= 0) | (v1 >= 0) | (v2 >= 0) | (v3 >= 0)) {
        if (v0 >= 0) {
            const float4* __restrict__ r = feat4 + (size_t)v0 * (Cv / 4) + c4b;
            const int vn = nxt[v0];
            a0[0] = fmax4(a0[0], r[0]); a0[1] = fmax4(a0[1], r[1]);
            a0[2] = fmax4(a0[2], r[2]); a0[3] = fmax4(a0[3], r[3]);
            v0 = vn;
        }
        if (v1 >= 0) {
            const float4* __restrict__ r = feat4 + (size_t)v1 * (Cv / 4) + c4b;
            const int vn = nxt[v1];
            a1[0] = fmax4(a1[0], r[0]); a1[1] = fmax4(a1[1], r[1]);
            a1[2] = fmax4(a1[2], r[2]); a1[3] = fmax4(a1[3], r[3]);
            v1 = vn;
        }
        if (v2 >= 0) {
            const float4* __restrict__ r = feat4 + (size_t)v2 * (Cv / 4) + c4b;
            const int vn = nxt[v2];
            a2[0] = fmax4(a2[0], r[0]); a2[1] = fmax4(a2[1], r[1]);
            a2[2] = fmax4(a2[2], r[2]); a2[3] = fmax4(a2[3], r[3]);
            v2 = vn;
        }
        if (v3 >= 0) {
            const float4* __restrict__ r = feat4 + (size_t)v3 * (Cv / 4) + c4b;
            const int vn = nxt[v3];
            a3[0] = fmax4(a3[0], r[0]); a3[1] = fmax4(a3[1], r[1]);
            a3[2] = fmax4(a3[2], r[2]); a3[3] = fmax4(a3[3], r[3]);
            v3 = vn;
        }
    }

    // Empty cells (head < 0): reference maps neginf -> 0.
    const float4 z4 = make_float4(0.f, 0.f, 0.f, 0.f);
    if (h.x < 0) { a0[0] = a0[1] = a0[2] = a0[3] = z4; }
    if (h.y < 0) { a1[0] = a1[1] = a1[2] = a1[3] = z4; }
    if (h.z < 0) { a2[0] = a2[1] = a2[2] = a2[3] = z4; }
    if (h.w < 0) { a3[0] = a3[1] = a3[2] = a3[3] = z4; }

    // Store: 4x4 in-register transpose -> NT float4 along spatial x.
    // out4 index = b*(Cv*Sv/4) + c*(Sv/4) + s0/4.
    const int obase = b * (Cv * (Sv / 4)) + (s0 >> 2);
    #pragma unroll
    for (int k = 0; k < 4; ++k) {
        const int c0 = (c4b + k) * 4;
        nt_store4(&out4[obase + (c0 + 0) * (Sv / 4)],
                  make_float4(a0[k].x, a1[k].x, a2[k].x, a3[k].x));
        nt_store4(&out4[obase + (c0 + 1) * (Sv / 4)],
                  make_float4(a0[k].y, a1[k].y, a2[k].y, a3[k].y));
        nt_store4(&out4[obase + (c0 + 2) * (Sv / 4)],
                  make_float4(a0[k].z, a1[k].z, a2[k].z, a3[k].z));
        nt_store4(&out4[obase + (c0 + 3) * (Sv / 4)],
                  make_float4(a0[k].w, a1[k].w, a2[k].w, a3[k].w));
    }
}

extern "C" void kernel_launch(void* const* d_in, const int* in_sizes, int n_in,
                              void* d_out, int out_size, void* d_ws, size_t ws_size,
                              hipStream_t stream) {
    const float* feat      = (const float*)d_in[0];   // (150000, 128) f32
    const int*   batch_idx = (const int*)d_in[1];
    const int*   y_idx     = (const int*)d_in[2];
    const int*   x_idx     = (const int*)d_in[3];
    // d_in[4] = batch_size scalar (compile-time Bv=4, unused)
    float* out = (float*)d_out;

    const int n_voxels = in_sizes[1];                 // 150000

    // Workspace layout: head[NCELLS] ints, next[n_voxels] ints (~3.2 MB).
    int* head = (int*)d_ws;
    int* nxt  = head + NCELLS;

    // head = -1 everywhere; next needs no init (written before any read).
    hipMemsetAsync(head, 0xFF, (size_t)NCELLS * sizeof(int), stream);

    build_lists_kernel<<<(n_voxels + 255) / 256, 256, 0, stream>>>(
        batch_idx, y_idx, x_idx, head, nxt, n_voxels);

    gather_max_kernel<<<NCELLS / TILE, 256, 0, stream>>>(
        (const float4*)feat, (const int4*)head, nxt, (float4*)out);
}